// Round 1
// baseline (329.500 us; speedup 1.0000x reference)
//
#include <hip/hip_runtime.h>
#include <math.h>

// Round 13: flash_partial de-staged. K/V fragments are wave-identical
// (no `w` in their addressing), the per-iter tile working set is 16KB
// (fits L1), and per-head K/V has heavy cross-block L2 reuse -> LDS
// staging was pure broadcast overhead plus two barrier drains per tile.
// Now: K/V fragments read straight from global (b128/lane), zero
// __syncthreads in the kernel, LDS = Pst only (17.4KB). launch_bounds
// (256,4) caps VGPR at 128 -> 4 blocks/CU resident.
// VALU trims: log2e folded into Q scale (raw exp2f), wave-uniform
// mask-skip for interior tiles, all-masked tiles skip exp, setprio(1)
// around MFMA clusters (T5 regime: independent waves, no lockstep).

typedef __bf16 bf16;
typedef __bf16 bf16x4 __attribute__((ext_vector_type(4)));
typedef __bf16 bf16x8 __attribute__((ext_vector_type(8)));
typedef float  f32x4  __attribute__((ext_vector_type(4)));

#define MFMA_BF16(a, b, c) __builtin_amdgcn_mfma_f32_16x16x32_bf16((a), (b), (c), 0, 0, 0)

#define SEQ  4096
#define NH   12
#define HD   64
#define DM   768
#define NQKV 2304
#define NPART 4
#define ATTN_SCALE 0.12f
#define LOG2E 1.4426950408889634f
#define RMS_EPS 1.1920928955078125e-07f

// ---------------------------------------------------------------------------
__global__ __launch_bounds__(256) void convert_in(const float* __restrict__ src,
                                                  bf16* __restrict__ dst, int n)
{
  const int i0 = (blockIdx.x * 256 + threadIdx.x) * 8;
  if (i0 >= n) return;
  f32x4 a = *(const f32x4*)(src + i0);
  f32x4 b = *(const f32x4*)(src + i0 + 4);
  bf16x8 o;
#pragma unroll
  for (int j = 0; j < 4; j++) { o[j] = (bf16)a[j]; o[j + 4] = (bf16)b[j]; }
  *(bf16x8*)(dst + i0) = o;
}

// ---------------------------------------------------------------------------
// 128x128-tile GEMM core (BK=32, 4 waves in 2x2 quadrants of 64x64).
// ---------------------------------------------------------------------------
__device__ __forceinline__ void gemm128_core(
    const bf16* __restrict__ A, const bf16* __restrict__ B,
    int m0, int n0, bf16 (*As)[40], bf16 (*Bs)[40], f32x4 acc[4][4])
{
  const int tid = threadIdx.x;
  const int lane = tid & 63, w = tid >> 6;
  const int c16 = lane & 15, q4 = lane >> 4;
  const int mo = (w & 1) * 64, no = (w >> 1) * 64;
  const int srow = tid >> 2, scol = (tid & 3) * 8;
  const f32x4 vzero = {0.f, 0.f, 0.f, 0.f};
#pragma unroll
  for (int i = 0; i < 4; i++)
#pragma unroll
    for (int j = 0; j < 4; j++) acc[i][j] = vzero;

  for (int k0 = 0; k0 < DM; k0 += 32) {
#pragma unroll
    for (int ps = 0; ps < 2; ps++) {
      const int r = srow + ps * 64;
      *(bf16x8*)&As[r][scol] = *(const bf16x8*)&A[(m0 + r) * DM + k0 + scol];
      *(bf16x8*)&Bs[r][scol] = *(const bf16x8*)&B[(n0 + r) * DM + k0 + scol];
    }
    __syncthreads();
    bf16x8 ar[4], br[4];
#pragma unroll
    for (int mq = 0; mq < 4; mq++)
      ar[mq] = *(const bf16x8*)&As[mo + mq * 16 + c16][q4 * 8];
#pragma unroll
    for (int nq = 0; nq < 4; nq++)
      br[nq] = *(const bf16x8*)&Bs[no + nq * 16 + c16][q4 * 8];
#pragma unroll
    for (int mq = 0; mq < 4; mq++)
#pragma unroll
      for (int nq = 0; nq < 4; nq++)
        acc[mq][nq] = MFMA_BF16(ar[mq], br[nq], acc[mq][nq]);
    __syncthreads();
  }
}

// QKV GEMM with FUSED norm+rope epilogue for Q/K (V written transposed raw).
// Q gets ATTN_SCALE * LOG2E folded in so flash can use raw exp2f.
__global__ __launch_bounds__(256) void gemm_qkv(
    const bf16* __restrict__ A, const bf16* __restrict__ B,
    bf16* __restrict__ Qb, bf16* __restrict__ Kb, bf16* __restrict__ Vt)
{
  __shared__ bf16 As[128][40];
  __shared__ bf16 Bs[128][40];
  const int m0 = blockIdx.x * 128, n0 = blockIdx.y * 128;
  f32x4 acc[4][4];
  gemm128_core(A, B, m0, n0, As, Bs, acc);

  const int lane = threadIdx.x & 63, w = threadIdx.x >> 6;
  const int c16 = lane & 15, q4 = lane >> 4;
  const int mo = (w & 1) * 64, no = (w >> 1) * 64;
  const int kidx = blockIdx.y / 6;
  const int rr0 = (n0 - kidx * DM) + no;     // multiple of 64: one full head
  const int h = rr0 >> 6;

  if (kidx == 2) {
#pragma unroll
    for (int nq = 0; nq < 4; nq++) {
      const int d = nq * 16 + c16;
#pragma unroll
      for (int mq = 0; mq < 4; mq++) {
        const int mb = m0 + mo + mq * 16 + q4 * 4;
#pragma unroll
        for (int rg = 0; rg < 4; rg++)
          Vt[((h * HD) + d) * SEQ + mb + rg] = (bf16)acc[mq][nq][rg];
      }
    }
  } else {
    bf16* dst = kidx ? Kb : Qb;
    const float scale = kidx ? 1.0f : (ATTN_SCALE * LOG2E);
    const float fr = exp2f(-10.0f * (float)c16 * (1.0f / 15.0f));
#pragma unroll
    for (int mq = 0; mq < 4; mq++) {
#pragma unroll
      for (int rg = 0; rg < 4; rg++) {
        const int m = m0 + mo + mq * 16 + q4 * 4 + rg;
        const float x0 = acc[mq][0][rg], x1 = acc[mq][1][rg];
        const float x2 = acc[mq][2][rg], x3 = acc[mq][3][rg];
        float ss = x0 * x0 + x1 * x1 + x2 * x2 + x3 * x3;
        ss += __shfl_xor(ss, 1, 64);
        ss += __shfl_xor(ss, 2, 64);
        ss += __shfl_xor(ss, 4, 64);
        ss += __shfl_xor(ss, 8, 64);
        const float rinv = rsqrtf(ss * (1.0f / 64.0f) + RMS_EPS) * scale;
        const float xn0 = x0 * rinv, xn1 = x1 * rinv;
        const float xn2 = x2 * rinv, xn3 = x3 * rinv;
        float sn, cs;
        sincosf((float)m * fr, &sn, &cs);
        const float y0 = xn0 * cs + xn2 * sn;
        const float y2 = xn2 * cs - xn0 * sn;
        bf16* rp = dst + (size_t)(h * SEQ + m) * HD + c16;
        rp[0]  = (bf16)y0;
        rp[16] = (bf16)xn1;
        rp[32] = (bf16)y2;
        rp[48] = (bf16)xn3;
      }
    }
  }
}

__global__ __launch_bounds__(256) void gemm_proj(
    const bf16* __restrict__ A, const bf16* __restrict__ B, float* __restrict__ C)
{
  __shared__ bf16 As[128][40];
  __shared__ bf16 Bs[128][40];
  const int m0 = blockIdx.x * 128, n0 = blockIdx.y * 128;
  f32x4 acc[4][4];
  gemm128_core(A, B, m0, n0, As, Bs, acc);

  const int lane = threadIdx.x & 63, w = threadIdx.x >> 6;
  const int c16 = lane & 15, q4 = lane >> 4;
  const int mo = (w & 1) * 64, no = (w >> 1) * 64;
#pragma unroll
  for (int nq = 0; nq < 4; nq++) {
    const int n = n0 + no + nq * 16 + c16;
#pragma unroll
    for (int mq = 0; mq < 4; mq++) {
      const int mb = m0 + mo + mq * 16 + q4 * 4;
#pragma unroll
      for (int rg = 0; rg < 4; rg++)
        C[(size_t)(mb + rg) * DM + n] = acc[mq][nq][rg];
    }
  }
}

// ---------------------------------------------------------------------------
// Flash partial, BM=128, S^T orientation, BARRIER-FREE.
// K/V fragments read directly from global (L1/L2-served; per-iter tile
// working set = 16KB, fits L1; identical across the 4 waves -> L1 reuse).
// Only LDS traffic is the per-wave-private Pst round-trip (no barrier:
// within-wave RAW ordered by lgkmcnt).
// ---------------------------------------------------------------------------
__global__ __launch_bounds__(256, 4) void flash_partial(
    const bf16* __restrict__ Qb, const bf16* __restrict__ Kb,
    const bf16* __restrict__ Vt, bf16* __restrict__ Opart,
    float* __restrict__ Lpart)
{
  __shared__ bf16 Pst[4][32][68];                 // [wave][q][s], stride 68: 8B-pair conflict-free
  const int h = blockIdx.y, p = blockIdx.z;
  const int qi = 31 - (int)blockIdx.x;            // LPT: heavy blocks first
  const int q0 = qi * 128;
  const int tid = threadIdx.x;
  const int lane = tid & 63, w = tid >> 6;
  const int c16 = lane & 15, q4 = lane >> 4;

  bf16x8 aq[2][2];
#pragma unroll
  for (int f = 0; f < 2; f++) {
    const int tq = q0 + w * 32 + f * 16 + c16;
    aq[f][0] = *(const bf16x8*)&Qb[((h * SEQ) + tq) * HD + q4 * 8];
    aq[f][1] = *(const bf16x8*)&Qb[((h * SEQ) + tq) * HD + 32 + q4 * 8];
  }
  const int qg[2] = { q0 + w * 32 + c16, q0 + w * 32 + 16 + c16 };  // this lane's q-row per f
  const int qb[2] = { q0 + w * 32,       q0 + w * 32 + 16 };        // wave-uniform min q-row per f

  const f32x4 vzero = {0.f, 0.f, 0.f, 0.f};
  f32x4 O[2][4];
  float l_f[2] = {0.f, 0.f};
#pragma unroll
  for (int f = 0; f < 2; f++)
#pragma unroll
    for (int j = 0; j < 4; j++) O[f][j] = vzero;

  const bf16* Kbase = Kb + (size_t)h * SEQ * HD;
  const bf16* Vbase = Vt + (size_t)h * HD * SEQ;

  const int sEnd = q0 + 64;
  const int sBeg = p * 64;

  for (int s0 = sBeg; s0 <= sEnd; s0 += NPART * 64) {
    // K fragments: A-operand [m=s][k=d], read once from global, shared by both f
    bf16x8 kf0[4], kf1[4];
#pragma unroll
    for (int nt = 0; nt < 4; nt++) {
      const bf16* kp = Kbase + (size_t)(s0 + nt * 16 + c16) * HD + q4 * 8;
      kf0[nt] = *(const bf16x8*)kp;
      kf1[nt] = *(const bf16x8*)(kp + 32);
    }
#pragma unroll
    for (int f = 0; f < 2; f++) {
      // S^T tile: D[m=s][n=q]; lane holds q=c16, s=nt*16+q4*4+rg
      f32x4 S[4];
      __builtin_amdgcn_s_setprio(1);
#pragma unroll
      for (int nt = 0; nt < 4; nt++) {
        f32x4 z = vzero;
        z = MFMA_BF16(kf0[nt], aq[f][0], z);
        z = MFMA_BF16(kf1[nt], aq[f][1], z);
        S[nt] = z;
      }
      __builtin_amdgcn_s_setprio(0);
      float lf = l_f[f];
      if (s0 + 63 <= qb[f]) {
        // interior tile: no masking needed for any lane of this wave
#pragma unroll
        for (int nt = 0; nt < 4; nt++) {
#pragma unroll
          for (int rg = 0; rg < 4; rg++) {
            const float pv = exp2f(S[nt][rg]);     // scale*log2e folded into Q
            S[nt][rg] = pv;
            lf += pv;
          }
          bf16x4 pk = { (bf16)S[nt][0], (bf16)S[nt][1], (bf16)S[nt][2], (bf16)S[nt][3] };
          *(bf16x4*)&Pst[w][f * 16 + c16][nt * 16 + q4 * 4] = pk;
        }
      } else if (s0 > qb[f] + 15) {
        // tile entirely above the diagonal for this wave/f: all masked
        const bf16x4 zk = { (bf16)0.f, (bf16)0.f, (bf16)0.f, (bf16)0.f };
#pragma unroll
        for (int nt = 0; nt < 4; nt++)
          *(bf16x4*)&Pst[w][f * 16 + c16][nt * 16 + q4 * 4] = zk;
      } else {
        // diagonal tile: per-element mask
#pragma unroll
        for (int nt = 0; nt < 4; nt++) {
#pragma unroll
          for (int rg = 0; rg < 4; rg++) {
            const int s_g = s0 + nt * 16 + q4 * 4 + rg;
            const float pv = (s_g > qg[f]) ? 0.f : exp2f(S[nt][rg]);
            S[nt][rg] = pv;
            lf += pv;
          }
          bf16x4 pk = { (bf16)S[nt][0], (bf16)S[nt][1], (bf16)S[nt][2], (bf16)S[nt][3] };
          *(bf16x4*)&Pst[w][f * 16 + c16][nt * 16 + q4 * 4] = pk;
        }
      }
      l_f[f] = lf;
    }
    // P fragments (A-op): contiguous b128 from Pst (wave-private, no barrier)
    bf16x8 ap[2][2];
#pragma unroll
    for (int f = 0; f < 2; f++) {
      ap[f][0] = *(const bf16x8*)&Pst[w][f * 16 + c16][q4 * 8];
      ap[f][1] = *(const bf16x8*)&Pst[w][f * 16 + c16][32 + q4 * 8];
    }
#pragma unroll
    for (int dt = 0; dt < 4; dt++) {
      // V fragments: B-operand [k=s][n=d], direct from global Vt [d][SEQ]
      const bf16* vp = Vbase + (size_t)(dt * 16 + c16) * SEQ + s0 + q4 * 8;
      bf16x8 bv0 = *(const bf16x8*)vp;
      bf16x8 bv1 = *(const bf16x8*)(vp + 32);
      __builtin_amdgcn_s_setprio(1);
#pragma unroll
      for (int f = 0; f < 2; f++) {
        O[f][dt] = MFMA_BF16(ap[f][0], bv0, O[f][dt]);
        O[f][dt] = MFMA_BF16(ap[f][1], bv1, O[f][dt]);
      }
      __builtin_amdgcn_s_setprio(0);
    }
  }

  // l: lane holds full sum for q-row c16 (per f) over its (q4, nt, rg) share
#pragma unroll
  for (int f = 0; f < 2; f++) {
    float l = l_f[f];
    l += __shfl_xor(l, 16, 64);
    l += __shfl_xor(l, 32, 64);
    l_f[f] = l;
  }
  const int u = ((h * 32 + qi) * NPART + p);
  bf16* Op = Opart + (size_t)u * 8192;            // 128 x 64
#pragma unroll
  for (int f = 0; f < 2; f++)
#pragma unroll
    for (int dt = 0; dt < 4; dt++)
#pragma unroll
      for (int rg = 0; rg < 4; rg++)
        Op[(w * 32 + f * 16 + q4 * 4 + rg) * 64 + dt * 16 + c16] = (bf16)O[f][dt][rg];
  if (lane < 32) {                                // q4 == 0 or 1 -> one writer per row
    if (q4 == 0) {
#pragma unroll
      for (int f = 0; f < 2; f++)
        Lpart[u * 128 + w * 32 + f * 16 + c16] = l_f[f];
    }
  }
}

// ---------------------------------------------------------------------------
// Combine: Y = (sum_p O_p) / (sum_p l_p). Block per 64-row chunk x head.
// ---------------------------------------------------------------------------
__global__ __launch_bounds__(256) void flash_combine(
    const bf16* __restrict__ Opart, const float* __restrict__ Lpart,
    bf16* __restrict__ Y)
{
  const int q64 = blockIdx.x, h = blockIdx.y;
  const int qi = q64 >> 1, roff = (q64 & 1) * 64;
  const int row = threadIdx.x >> 2, cg = (threadIdx.x & 3) * 16;
  const int u0 = (h * 32 + qi) * NPART;
  const int r128 = roff + row;
  float lsum = 0.f;
#pragma unroll
  for (int p = 0; p < NPART; p++) lsum += Lpart[(u0 + p) * 128 + r128];
  const float inv = 1.0f / lsum;
  const bf16* O0 = Opart + (size_t)u0 * 8192 + r128 * 64 + cg;
  bf16* yp = Y + (size_t)(q64 * 64 + row) * DM + h * HD + cg;
#pragma unroll
  for (int j = 0; j < 16; j += 8) {
    float s[8] = {0, 0, 0, 0, 0, 0, 0, 0};
#pragma unroll
    for (int p = 0; p < NPART; p++) {
      bf16x8 a = *(const bf16x8*)(O0 + p * 8192 + j);
#pragma unroll
      for (int e = 0; e < 8; e++) s[e] += (float)a[e];
    }
#pragma unroll
    for (int e = 0; e < 8; e++) yp[j + e] = (bf16)(s[e] * inv);
  }
}

// ---------------------------------------------------------------------------
extern "C" void kernel_launch(void* const* d_in, const int* in_sizes, int n_in,
                              void* d_out, int out_size, void* d_ws, size_t ws_size,
                              hipStream_t stream)
{
  (void)in_sizes; (void)n_in; (void)out_size; (void)ws_size;
  const float* x      = (const float*)d_in[0];
  const float* qkvw   = (const float*)d_in[1];
  const float* cprojw = (const float*)d_in[2];
  float* outp = (float*)d_out;

  const int NX = SEQ * DM, NW = NQKV * DM, NP = DM * DM;

  char* ws = (char*)d_ws;
  bf16*  xb    = (bf16*)(ws);                       // 6,291,456
  bf16*  wqkv  = (bf16*)(ws + 6291456);             // 3,538,944
  bf16*  wproj = (bf16*)(ws + 9830400);             // 1,179,648
  bf16*  Q     = (bf16*)(ws + 11010048);            // 6,291,456
  bf16*  K     = (bf16*)(ws + 17301504);            // 6,291,456
  bf16*  Vt    = (bf16*)(ws + 23592960);            // 6,291,456
  bf16*  Y     = (bf16*)(ws + 29884416);            // 6,291,456
  bf16*  Opart = (bf16*)(ws + 36175872);            // 25,165,824 (1536 x 8192 bf16)
  float* Lpart = (float*)(ws + 61341696);           //    786,432  (total 62.1 MB)

  convert_in<<<dim3(NX / 2048), 256, 0, stream>>>(x,      xb,    NX);
  convert_in<<<dim3(NW / 2048), 256, 0, stream>>>(qkvw,   wqkv,  NW);
  convert_in<<<dim3(NP / 2048), 256, 0, stream>>>(cprojw, wproj, NP);

  gemm_qkv     <<<dim3(SEQ / 128, NQKV / 128), 256, 0, stream>>>(xb, wqkv, Q, K, Vt);
  flash_partial<<<dim3(SEQ / 128, NH, NPART),  256, 0, stream>>>(Q, K, Vt, Opart, Lpart);
  flash_combine<<<dim3(SEQ / 64, NH),          256, 0, stream>>>(Opart, Lpart, Y);
  gemm_proj    <<<dim3(SEQ / 128, DM / 128),   256, 0, stream>>>(Y, wproj, outp);
}

// Round 2
// 186.269 us; speedup vs baseline: 1.7689x; 1.7689x over previous
//
#include <hip/hip_runtime.h>
#include <math.h>

// Round 14: R13 post-mortem — de-staging removed latency hiding (MfmaUtil
// 12->5). Reverted to R12's staged+prefetch flash structure, KEEPING R13's
// sound VALU trims (exp2f with log2e folded into Q scale; 3-way mask-skip).
// New attack: work balance. R12 ran 1536 blocks with 0..17-tile trip counts
// -> long tail, avg occupancy 13.8% vs 50% possible. Now each block processes
// the COMPLEMENTARY q-tile pair (31-j, then j): per-block work is uniform
// (16-18 tiles), grid = 768 blocks = 3/CU all co-resident, no tail.

typedef __bf16 bf16;
typedef __bf16 bf16x4 __attribute__((ext_vector_type(4)));
typedef __bf16 bf16x8 __attribute__((ext_vector_type(8)));
typedef float  f32x4  __attribute__((ext_vector_type(4)));

#define MFMA_BF16(a, b, c) __builtin_amdgcn_mfma_f32_16x16x32_bf16((a), (b), (c), 0, 0, 0)

#define SEQ  4096
#define NH   12
#define HD   64
#define DM   768
#define NQKV 2304
#define NPART 4
#define ATTN_SCALE 0.12f
#define LOG2E 1.4426950408889634f
#define RMS_EPS 1.1920928955078125e-07f

// ---------------------------------------------------------------------------
__global__ __launch_bounds__(256) void convert_in(const float* __restrict__ src,
                                                  bf16* __restrict__ dst, int n)
{
  const int i0 = (blockIdx.x * 256 + threadIdx.x) * 8;
  if (i0 >= n) return;
  f32x4 a = *(const f32x4*)(src + i0);
  f32x4 b = *(const f32x4*)(src + i0 + 4);
  bf16x8 o;
#pragma unroll
  for (int j = 0; j < 4; j++) { o[j] = (bf16)a[j]; o[j + 4] = (bf16)b[j]; }
  *(bf16x8*)(dst + i0) = o;
}

// ---------------------------------------------------------------------------
// 128x128-tile GEMM core (BK=32, 4 waves in 2x2 quadrants of 64x64).
// ---------------------------------------------------------------------------
__device__ __forceinline__ void gemm128_core(
    const bf16* __restrict__ A, const bf16* __restrict__ B,
    int m0, int n0, bf16 (*As)[40], bf16 (*Bs)[40], f32x4 acc[4][4])
{
  const int tid = threadIdx.x;
  const int lane = tid & 63, w = tid >> 6;
  const int c16 = lane & 15, q4 = lane >> 4;
  const int mo = (w & 1) * 64, no = (w >> 1) * 64;
  const int srow = tid >> 2, scol = (tid & 3) * 8;
  const f32x4 vzero = {0.f, 0.f, 0.f, 0.f};
#pragma unroll
  for (int i = 0; i < 4; i++)
#pragma unroll
    for (int j = 0; j < 4; j++) acc[i][j] = vzero;

  for (int k0 = 0; k0 < DM; k0 += 32) {
#pragma unroll
    for (int ps = 0; ps < 2; ps++) {
      const int r = srow + ps * 64;
      *(bf16x8*)&As[r][scol] = *(const bf16x8*)&A[(m0 + r) * DM + k0 + scol];
      *(bf16x8*)&Bs[r][scol] = *(const bf16x8*)&B[(n0 + r) * DM + k0 + scol];
    }
    __syncthreads();
    bf16x8 ar[4], br[4];
#pragma unroll
    for (int mq = 0; mq < 4; mq++)
      ar[mq] = *(const bf16x8*)&As[mo + mq * 16 + c16][q4 * 8];
#pragma unroll
    for (int nq = 0; nq < 4; nq++)
      br[nq] = *(const bf16x8*)&Bs[no + nq * 16 + c16][q4 * 8];
#pragma unroll
    for (int mq = 0; mq < 4; mq++)
#pragma unroll
      for (int nq = 0; nq < 4; nq++)
        acc[mq][nq] = MFMA_BF16(ar[mq], br[nq], acc[mq][nq]);
    __syncthreads();
  }
}

// QKV GEMM with FUSED norm+rope epilogue for Q/K (V written transposed raw).
// Q gets ATTN_SCALE * LOG2E folded in so flash can use raw exp2f.
__global__ __launch_bounds__(256) void gemm_qkv(
    const bf16* __restrict__ A, const bf16* __restrict__ B,
    bf16* __restrict__ Qb, bf16* __restrict__ Kb, bf16* __restrict__ Vt)
{
  __shared__ bf16 As[128][40];
  __shared__ bf16 Bs[128][40];
  const int m0 = blockIdx.x * 128, n0 = blockIdx.y * 128;
  f32x4 acc[4][4];
  gemm128_core(A, B, m0, n0, As, Bs, acc);

  const int lane = threadIdx.x & 63, w = threadIdx.x >> 6;
  const int c16 = lane & 15, q4 = lane >> 4;
  const int mo = (w & 1) * 64, no = (w >> 1) * 64;
  const int kidx = blockIdx.y / 6;
  const int rr0 = (n0 - kidx * DM) + no;     // multiple of 64: one full head
  const int h = rr0 >> 6;

  if (kidx == 2) {
#pragma unroll
    for (int nq = 0; nq < 4; nq++) {
      const int d = nq * 16 + c16;
#pragma unroll
      for (int mq = 0; mq < 4; mq++) {
        const int mb = m0 + mo + mq * 16 + q4 * 4;
#pragma unroll
        for (int rg = 0; rg < 4; rg++)
          Vt[((h * HD) + d) * SEQ + mb + rg] = (bf16)acc[mq][nq][rg];
      }
    }
  } else {
    bf16* dst = kidx ? Kb : Qb;
    const float scale = kidx ? 1.0f : (ATTN_SCALE * LOG2E);
    const float fr = exp2f(-10.0f * (float)c16 * (1.0f / 15.0f));
#pragma unroll
    for (int mq = 0; mq < 4; mq++) {
#pragma unroll
      for (int rg = 0; rg < 4; rg++) {
        const int m = m0 + mo + mq * 16 + q4 * 4 + rg;
        const float x0 = acc[mq][0][rg], x1 = acc[mq][1][rg];
        const float x2 = acc[mq][2][rg], x3 = acc[mq][3][rg];
        float ss = x0 * x0 + x1 * x1 + x2 * x2 + x3 * x3;
        ss += __shfl_xor(ss, 1, 64);
        ss += __shfl_xor(ss, 2, 64);
        ss += __shfl_xor(ss, 4, 64);
        ss += __shfl_xor(ss, 8, 64);
        const float rinv = rsqrtf(ss * (1.0f / 64.0f) + RMS_EPS) * scale;
        const float xn0 = x0 * rinv, xn1 = x1 * rinv;
        const float xn2 = x2 * rinv, xn3 = x3 * rinv;
        float sn, cs;
        sincosf((float)m * fr, &sn, &cs);
        const float y0 = xn0 * cs + xn2 * sn;
        const float y2 = xn2 * cs - xn0 * sn;
        bf16* rp = dst + (size_t)(h * SEQ + m) * HD + c16;
        rp[0]  = (bf16)y0;
        rp[16] = (bf16)xn1;
        rp[32] = (bf16)y2;
        rp[48] = (bf16)xn3;
      }
    }
  }
}

__global__ __launch_bounds__(256) void gemm_proj(
    const bf16* __restrict__ A, const bf16* __restrict__ B, float* __restrict__ C)
{
  __shared__ bf16 As[128][40];
  __shared__ bf16 Bs[128][40];
  const int m0 = blockIdx.x * 128, n0 = blockIdx.y * 128;
  f32x4 acc[4][4];
  gemm128_core(A, B, m0, n0, As, Bs, acc);

  const int lane = threadIdx.x & 63, w = threadIdx.x >> 6;
  const int c16 = lane & 15, q4 = lane >> 4;
  const int mo = (w & 1) * 64, no = (w >> 1) * 64;
#pragma unroll
  for (int nq = 0; nq < 4; nq++) {
    const int n = n0 + no + nq * 16 + c16;
#pragma unroll
    for (int mq = 0; mq < 4; mq++) {
      const int mb = m0 + mo + mq * 16 + q4 * 4;
#pragma unroll
      for (int rg = 0; rg < 4; rg++)
        C[(size_t)(mb + rg) * DM + n] = acc[mq][nq][rg];
    }
  }
}

// ---------------------------------------------------------------------------
// Flash partial, BM=128, S^T orientation, staged + register-prefetched (R12
// structure). Block = (pair j, h, p); processes q-tile 31-j then q-tile j:
// per-(j,p) total trip count is 16-18 tiles -> uniform block cost, 768
// blocks = 3/CU co-resident, no dispatch tail.
// ---------------------------------------------------------------------------
__global__ __launch_bounds__(256, 3) void flash_partial(
    const bf16* __restrict__ Qb, const bf16* __restrict__ Kb,
    const bf16* __restrict__ Vt, bf16* __restrict__ Opart,
    float* __restrict__ Lpart)
{
  __shared__ bf16 Ks[64][72];
  __shared__ bf16 Vts[64][72];
  __shared__ bf16 Pst[4][32][68];                 // [wave][q][s], stride 68: 8B-pair conflict-free
  const int h = blockIdx.y, p = blockIdx.z;
  const int jb = blockIdx.x;                      // 0..15: pair (31-jb, jb)
  const int tid = threadIdx.x;
  const int lane = tid & 63, w = tid >> 6;
  const int c16 = lane & 15, q4 = lane >> 4;
  const int sr = tid >> 3, sc8 = (tid & 7) * 8;

  const bf16* Kbase = Kb + (size_t)h * SEQ * HD;
  const bf16* Vbase = Vt + (size_t)h * HD * SEQ;
  const f32x4 vzero = {0.f, 0.f, 0.f, 0.f};

#pragma unroll 1
  for (int half = 0; half < 2; ++half) {
    const int qi = half ? jb : (31 - jb);         // heavy q-tile first
    const int q0 = qi * 128;

    bf16x8 aq[2][2];
#pragma unroll
    for (int f = 0; f < 2; f++) {
      const int tq = q0 + w * 32 + f * 16 + c16;
      aq[f][0] = *(const bf16x8*)&Qb[((h * SEQ) + tq) * HD + q4 * 8];
      aq[f][1] = *(const bf16x8*)&Qb[((h * SEQ) + tq) * HD + 32 + q4 * 8];
    }
    const int qg[2] = { q0 + w * 32 + c16, q0 + w * 32 + 16 + c16 };  // lane's q-row per f
    const int qb[2] = { q0 + w * 32,       q0 + w * 32 + 16 };        // wave-uniform min q-row

    f32x4 O[2][4];
    float l_f[2] = {0.f, 0.f};
#pragma unroll
    for (int f = 0; f < 2; f++)
#pragma unroll
      for (int j = 0; j < 4; j++) O[f][j] = vzero;

    const int sEnd = q0 + 64;
    const int sBeg = p * 64;
    if (sBeg <= sEnd) {
      bf16x8 kr0 = *(const bf16x8*)&Kbase[(sBeg + sr) * HD + sc8];
      bf16x8 kr1 = *(const bf16x8*)&Kbase[(sBeg + sr + 32) * HD + sc8];
      bf16x8 vr0 = *(const bf16x8*)&Vbase[sr * SEQ + sBeg + sc8];
      bf16x8 vr1 = *(const bf16x8*)&Vbase[(sr + 32) * SEQ + sBeg + sc8];

      for (int s0 = sBeg; s0 <= sEnd; s0 += NPART * 64) {
        __syncthreads();
        *(bf16x8*)&Ks[sr][sc8]       = kr0;
        *(bf16x8*)&Ks[sr + 32][sc8]  = kr1;
        *(bf16x8*)&Vts[sr][sc8]      = vr0;
        *(bf16x8*)&Vts[sr + 32][sc8] = vr1;
        __syncthreads();

        const int snext = s0 + NPART * 64;
        if (snext <= sEnd) {
          kr0 = *(const bf16x8*)&Kbase[(snext + sr) * HD + sc8];
          kr1 = *(const bf16x8*)&Kbase[(snext + sr + 32) * HD + sc8];
          vr0 = *(const bf16x8*)&Vbase[sr * SEQ + snext + sc8];
          vr1 = *(const bf16x8*)&Vbase[(sr + 32) * SEQ + snext + sc8];
        }

        // K fragments: A-operand [m=s][k=d], read once, shared by both f
        bf16x8 kf0[4], kf1[4];
#pragma unroll
        for (int nt = 0; nt < 4; nt++) {
          kf0[nt] = *(const bf16x8*)&Ks[nt * 16 + c16][q4 * 8];
          kf1[nt] = *(const bf16x8*)&Ks[nt * 16 + c16][32 + q4 * 8];
        }
#pragma unroll
        for (int f = 0; f < 2; f++) {
          // S^T tile: D[m=s][n=q]; lane holds q=c16, s=nt*16+q4*4+rg
          f32x4 S[4];
          __builtin_amdgcn_s_setprio(1);
#pragma unroll
          for (int nt = 0; nt < 4; nt++) {
            f32x4 z = vzero;
            z = MFMA_BF16(kf0[nt], aq[f][0], z);
            z = MFMA_BF16(kf1[nt], aq[f][1], z);
            S[nt] = z;
          }
          __builtin_amdgcn_s_setprio(0);
          float lf = l_f[f];
          if (s0 + 63 <= qb[f]) {
            // interior tile: no lane of this wave/f is masked
#pragma unroll
            for (int nt = 0; nt < 4; nt++) {
#pragma unroll
              for (int rg = 0; rg < 4; rg++) {
                const float pv = exp2f(S[nt][rg]);   // scale*log2e folded into Q
                S[nt][rg] = pv;
                lf += pv;
              }
              bf16x4 pk = { (bf16)S[nt][0], (bf16)S[nt][1], (bf16)S[nt][2], (bf16)S[nt][3] };
              *(bf16x4*)&Pst[w][f * 16 + c16][nt * 16 + q4 * 4] = pk;
            }
          } else if (s0 > qb[f] + 15) {
            // tile entirely above the diagonal for this wave/f: all masked
            const bf16x4 zk = { (bf16)0.f, (bf16)0.f, (bf16)0.f, (bf16)0.f };
#pragma unroll
            for (int nt = 0; nt < 4; nt++)
              *(bf16x4*)&Pst[w][f * 16 + c16][nt * 16 + q4 * 4] = zk;
          } else {
            // diagonal tile: per-element mask
#pragma unroll
            for (int nt = 0; nt < 4; nt++) {
#pragma unroll
              for (int rg = 0; rg < 4; rg++) {
                const int s_g = s0 + nt * 16 + q4 * 4 + rg;
                const float pv = (s_g > qg[f]) ? 0.f : exp2f(S[nt][rg]);
                S[nt][rg] = pv;
                lf += pv;
              }
              bf16x4 pk = { (bf16)S[nt][0], (bf16)S[nt][1], (bf16)S[nt][2], (bf16)S[nt][3] };
              *(bf16x4*)&Pst[w][f * 16 + c16][nt * 16 + q4 * 4] = pk;
            }
          }
          l_f[f] = lf;
        }
        // P fragments (A-op): contiguous b128 from Pst (wave-private)
        bf16x8 ap[2][2];
#pragma unroll
        for (int f = 0; f < 2; f++) {
          ap[f][0] = *(const bf16x8*)&Pst[w][f * 16 + c16][q4 * 8];
          ap[f][1] = *(const bf16x8*)&Pst[w][f * 16 + c16][32 + q4 * 8];
        }
#pragma unroll
        for (int dt = 0; dt < 4; dt++) {
          bf16x8 bv0 = *(const bf16x8*)&Vts[dt * 16 + c16][q4 * 8];
          bf16x8 bv1 = *(const bf16x8*)&Vts[dt * 16 + c16][32 + q4 * 8];
          __builtin_amdgcn_s_setprio(1);
#pragma unroll
          for (int f = 0; f < 2; f++) {
            O[f][dt] = MFMA_BF16(ap[f][0], bv0, O[f][dt]);
            O[f][dt] = MFMA_BF16(ap[f][1], bv1, O[f][dt]);
          }
          __builtin_amdgcn_s_setprio(0);
        }
      }
    }

    // l: lane holds full sum for q-row c16 (per f) over its (q4, nt, rg) share
#pragma unroll
    for (int f = 0; f < 2; f++) {
      float l = l_f[f];
      l += __shfl_xor(l, 16, 64);
      l += __shfl_xor(l, 32, 64);
      l_f[f] = l;
    }
    const int u = ((h * 32 + qi) * NPART + p);
    bf16* Op = Opart + (size_t)u * 8192;            // 128 x 64
#pragma unroll
    for (int f = 0; f < 2; f++)
#pragma unroll
      for (int dt = 0; dt < 4; dt++)
#pragma unroll
        for (int rg = 0; rg < 4; rg++)
          Op[(w * 32 + f * 16 + q4 * 4 + rg) * 64 + dt * 16 + c16] = (bf16)O[f][dt][rg];
    if (lane < 32) {                                // q4 == 0 -> one writer per row
      if (q4 == 0) {
#pragma unroll
        for (int f = 0; f < 2; f++)
          Lpart[u * 128 + w * 32 + f * 16 + c16] = l_f[f];
      }
    }
  }
}

// ---------------------------------------------------------------------------
// Combine: Y = (sum_p O_p) / (sum_p l_p). Block per 64-row chunk x head.
// ---------------------------------------------------------------------------
__global__ __launch_bounds__(256) void flash_combine(
    const bf16* __restrict__ Opart, const float* __restrict__ Lpart,
    bf16* __restrict__ Y)
{
  const int q64 = blockIdx.x, h = blockIdx.y;
  const int qi = q64 >> 1, roff = (q64 & 1) * 64;
  const int row = threadIdx.x >> 2, cg = (threadIdx.x & 3) * 16;
  const int u0 = (h * 32 + qi) * NPART;
  const int r128 = roff + row;
  float lsum = 0.f;
#pragma unroll
  for (int p = 0; p < NPART; p++) lsum += Lpart[(u0 + p) * 128 + r128];
  const float inv = 1.0f / lsum;
  const bf16* O0 = Opart + (size_t)u0 * 8192 + r128 * 64 + cg;
  bf16* yp = Y + (size_t)(q64 * 64 + row) * DM + h * HD + cg;
#pragma unroll
  for (int j = 0; j < 16; j += 8) {
    float s[8] = {0, 0, 0, 0, 0, 0, 0, 0};
#pragma unroll
    for (int p = 0; p < NPART; p++) {
      bf16x8 a = *(const bf16x8*)(O0 + p * 8192 + j);
#pragma unroll
      for (int e = 0; e < 8; e++) s[e] += (float)a[e];
    }
#pragma unroll
    for (int e = 0; e < 8; e++) yp[j + e] = (bf16)(s[e] * inv);
  }
}

// ---------------------------------------------------------------------------
extern "C" void kernel_launch(void* const* d_in, const int* in_sizes, int n_in,
                              void* d_out, int out_size, void* d_ws, size_t ws_size,
                              hipStream_t stream)
{
  (void)in_sizes; (void)n_in; (void)out_size; (void)ws_size;
  const float* x      = (const float*)d_in[0];
  const float* qkvw   = (const float*)d_in[1];
  const float* cprojw = (const float*)d_in[2];
  float* outp = (float*)d_out;

  const int NX = SEQ * DM, NW = NQKV * DM, NP = DM * DM;

  char* ws = (char*)d_ws;
  bf16*  xb    = (bf16*)(ws);                       // 6,291,456
  bf16*  wqkv  = (bf16*)(ws + 6291456);             // 3,538,944
  bf16*  wproj = (bf16*)(ws + 9830400);             // 1,179,648
  bf16*  Q     = (bf16*)(ws + 11010048);            // 6,291,456
  bf16*  K     = (bf16*)(ws + 17301504);            // 6,291,456
  bf16*  Vt    = (bf16*)(ws + 23592960);            // 6,291,456
  bf16*  Y     = (bf16*)(ws + 29884416);            // 6,291,456
  bf16*  Opart = (bf16*)(ws + 36175872);            // 25,165,824 (1536 x 8192 bf16)
  float* Lpart = (float*)(ws + 61341696);           //    786,432  (total 62.1 MB)

  convert_in<<<dim3(NX / 2048), 256, 0, stream>>>(x,      xb,    NX);
  convert_in<<<dim3(NW / 2048), 256, 0, stream>>>(qkvw,   wqkv,  NW);
  convert_in<<<dim3(NP / 2048), 256, 0, stream>>>(cprojw, wproj, NP);

  gemm_qkv     <<<dim3(SEQ / 128, NQKV / 128), 256, 0, stream>>>(xb, wqkv, Q, K, Vt);
  flash_partial<<<dim3(16, NH, NPART),         256, 0, stream>>>(Q, K, Vt, Opart, Lpart);
  flash_combine<<<dim3(SEQ / 64, NH),          256, 0, stream>>>(Opart, Lpart, Y);
  gemm_proj    <<<dim3(SEQ / 128, DM / 128),   256, 0, stream>>>(Y, wproj, outp);
}

// Round 3
// 180.516 us; speedup vs baseline: 1.8253x; 1.0319x over previous
//
#include <hip/hip_runtime.h>
#include <math.h>

// Round 15: gemm core staging converted from reg-staging (global->VGPR->
// ds_write) to __builtin_amdgcn_global_load_lds width=16 (m93->m97 lever:
// +69% on this exact 128^2 2-barrier structure). LDS tiles unpadded
// [128][32] (gload_lds writes lane-linearly: byte off = tid*16; padding
// would corrupt). Fragment b128 reads on the unpadded tile are bank-
// BALANCED (8 lanes x 8 four-bank groups = b128 issue floor). Flash
// kernel unchanged from R14 (one variable per round).

typedef __bf16 bf16;
typedef __bf16 bf16x4 __attribute__((ext_vector_type(4)));
typedef __bf16 bf16x8 __attribute__((ext_vector_type(8)));
typedef float  f32x4  __attribute__((ext_vector_type(4)));

#define MFMA_BF16(a, b, c) __builtin_amdgcn_mfma_f32_16x16x32_bf16((a), (b), (c), 0, 0, 0)

#define SEQ  4096
#define NH   12
#define HD   64
#define DM   768
#define NQKV 2304
#define NPART 4
#define ATTN_SCALE 0.12f
#define LOG2E 1.4426950408889634f
#define RMS_EPS 1.1920928955078125e-07f

typedef __attribute__((address_space(3))) void  lds_void;
typedef const __attribute__((address_space(1))) void g_void;

__device__ __forceinline__ void gload16(const void* g, void* l)
{
  __builtin_amdgcn_global_load_lds((g_void*)g, (lds_void*)l, 16, 0, 0);
}

// ---------------------------------------------------------------------------
__global__ __launch_bounds__(256) void convert_in(const float* __restrict__ src,
                                                  bf16* __restrict__ dst, int n)
{
  const int i0 = (blockIdx.x * 256 + threadIdx.x) * 8;
  if (i0 >= n) return;
  f32x4 a = *(const f32x4*)(src + i0);
  f32x4 b = *(const f32x4*)(src + i0 + 4);
  bf16x8 o;
#pragma unroll
  for (int j = 0; j < 4; j++) { o[j] = (bf16)a[j]; o[j + 4] = (bf16)b[j]; }
  *(bf16x8*)(dst + i0) = o;
}

// ---------------------------------------------------------------------------
// 128x128-tile GEMM core (BK=32, 4 waves in 2x2 quadrants of 64x64).
// Staging: direct global->LDS DMA, 4x16B per thread per k-step.
// ---------------------------------------------------------------------------
__device__ __forceinline__ void gemm128_core(
    const bf16* __restrict__ A, const bf16* __restrict__ B,
    int m0, int n0, bf16 (*As)[32], bf16 (*Bs)[32], f32x4 acc[4][4])
{
  const int tid = threadIdx.x;
  const int lane = tid & 63, w = tid >> 6;
  const int c16 = lane & 15, q4 = lane >> 4;
  const int mo = (w & 1) * 64, no = (w >> 1) * 64;
  const int srow = tid >> 2, scol = (tid & 3) * 8;   // LDS byte off = tid*16 (lane-linear)
  const f32x4 vzero = {0.f, 0.f, 0.f, 0.f};
#pragma unroll
  for (int i = 0; i < 4; i++)
#pragma unroll
    for (int j = 0; j < 4; j++) acc[i][j] = vzero;

  const bf16* aBase = A + (size_t)(m0 + srow) * DM + scol;
  const bf16* bBase = B + (size_t)(n0 + srow) * DM + scol;

  for (int k0 = 0; k0 < DM; k0 += 32) {
    gload16(aBase + k0,                 &As[srow][scol]);
    gload16(aBase + (size_t)64 * DM + k0, &As[srow + 64][scol]);
    gload16(bBase + k0,                 &Bs[srow][scol]);
    gload16(bBase + (size_t)64 * DM + k0, &Bs[srow + 64][scol]);
    __syncthreads();                     // drains vmcnt -> LDS tiles complete
    bf16x8 ar[4], br[4];
#pragma unroll
    for (int mq = 0; mq < 4; mq++)
      ar[mq] = *(const bf16x8*)&As[mo + mq * 16 + c16][q4 * 8];
#pragma unroll
    for (int nq = 0; nq < 4; nq++)
      br[nq] = *(const bf16x8*)&Bs[no + nq * 16 + c16][q4 * 8];
#pragma unroll
    for (int mq = 0; mq < 4; mq++)
#pragma unroll
      for (int nq = 0; nq < 4; nq++)
        acc[mq][nq] = MFMA_BF16(ar[mq], br[nq], acc[mq][nq]);
    __syncthreads();                     // all reads done before next writes
  }
}

// QKV GEMM with FUSED norm+rope epilogue for Q/K (V written transposed raw).
// Q gets ATTN_SCALE * LOG2E folded in so flash can use raw exp2f.
__global__ __launch_bounds__(256) void gemm_qkv(
    const bf16* __restrict__ A, const bf16* __restrict__ B,
    bf16* __restrict__ Qb, bf16* __restrict__ Kb, bf16* __restrict__ Vt)
{
  __shared__ bf16 As[128][32];
  __shared__ bf16 Bs[128][32];
  const int m0 = blockIdx.x * 128, n0 = blockIdx.y * 128;
  f32x4 acc[4][4];
  gemm128_core(A, B, m0, n0, As, Bs, acc);

  const int lane = threadIdx.x & 63, w = threadIdx.x >> 6;
  const int c16 = lane & 15, q4 = lane >> 4;
  const int mo = (w & 1) * 64, no = (w >> 1) * 64;
  const int kidx = blockIdx.y / 6;
  const int rr0 = (n0 - kidx * DM) + no;     // multiple of 64: one full head
  const int h = rr0 >> 6;

  if (kidx == 2) {
#pragma unroll
    for (int nq = 0; nq < 4; nq++) {
      const int d = nq * 16 + c16;
#pragma unroll
      for (int mq = 0; mq < 4; mq++) {
        const int mb = m0 + mo + mq * 16 + q4 * 4;
#pragma unroll
        for (int rg = 0; rg < 4; rg++)
          Vt[((h * HD) + d) * SEQ + mb + rg] = (bf16)acc[mq][nq][rg];
      }
    }
  } else {
    bf16* dst = kidx ? Kb : Qb;
    const float scale = kidx ? 1.0f : (ATTN_SCALE * LOG2E);
    const float fr = exp2f(-10.0f * (float)c16 * (1.0f / 15.0f));
#pragma unroll
    for (int mq = 0; mq < 4; mq++) {
#pragma unroll
      for (int rg = 0; rg < 4; rg++) {
        const int m = m0 + mo + mq * 16 + q4 * 4 + rg;
        const float x0 = acc[mq][0][rg], x1 = acc[mq][1][rg];
        const float x2 = acc[mq][2][rg], x3 = acc[mq][3][rg];
        float ss = x0 * x0 + x1 * x1 + x2 * x2 + x3 * x3;
        ss += __shfl_xor(ss, 1, 64);
        ss += __shfl_xor(ss, 2, 64);
        ss += __shfl_xor(ss, 4, 64);
        ss += __shfl_xor(ss, 8, 64);
        const float rinv = rsqrtf(ss * (1.0f / 64.0f) + RMS_EPS) * scale;
        const float xn0 = x0 * rinv, xn1 = x1 * rinv;
        const float xn2 = x2 * rinv, xn3 = x3 * rinv;
        float sn, cs;
        sincosf((float)m * fr, &sn, &cs);
        const float y0 = xn0 * cs + xn2 * sn;
        const float y2 = xn2 * cs - xn0 * sn;
        bf16* rp = dst + (size_t)(h * SEQ + m) * HD + c16;
        rp[0]  = (bf16)y0;
        rp[16] = (bf16)xn1;
        rp[32] = (bf16)y2;
        rp[48] = (bf16)xn3;
      }
    }
  }
}

__global__ __launch_bounds__(256) void gemm_proj(
    const bf16* __restrict__ A, const bf16* __restrict__ B, float* __restrict__ C)
{
  __shared__ bf16 As[128][32];
  __shared__ bf16 Bs[128][32];
  const int m0 = blockIdx.x * 128, n0 = blockIdx.y * 128;
  f32x4 acc[4][4];
  gemm128_core(A, B, m0, n0, As, Bs, acc);

  const int lane = threadIdx.x & 63, w = threadIdx.x >> 6;
  const int c16 = lane & 15, q4 = lane >> 4;
  const int mo = (w & 1) * 64, no = (w >> 1) * 64;
#pragma unroll
  for (int nq = 0; nq < 4; nq++) {
    const int n = n0 + no + nq * 16 + c16;
#pragma unroll
    for (int mq = 0; mq < 4; mq++) {
      const int mb = m0 + mo + mq * 16 + q4 * 4;
#pragma unroll
      for (int rg = 0; rg < 4; rg++)
        C[(size_t)(mb + rg) * DM + n] = acc[mq][nq][rg];
    }
  }
}

// ---------------------------------------------------------------------------
// Flash partial, BM=128, S^T orientation, staged + register-prefetched.
// Block = (pair j, h, p); processes q-tile 31-j then q-tile j: per-(j,p)
// total trip count is 16-18 tiles -> uniform block cost, 768 blocks = 3/CU
// co-resident, no dispatch tail. (Unchanged from R14.)
// ---------------------------------------------------------------------------
__global__ __launch_bounds__(256, 3) void flash_partial(
    const bf16* __restrict__ Qb, const bf16* __restrict__ Kb,
    const bf16* __restrict__ Vt, bf16* __restrict__ Opart,
    float* __restrict__ Lpart)
{
  __shared__ bf16 Ks[64][72];
  __shared__ bf16 Vts[64][72];
  __shared__ bf16 Pst[4][32][68];                 // [wave][q][s], stride 68: 8B-pair conflict-free
  const int h = blockIdx.y, p = blockIdx.z;
  const int jb = blockIdx.x;                      // 0..15: pair (31-jb, jb)
  const int tid = threadIdx.x;
  const int lane = tid & 63, w = tid >> 6;
  const int c16 = lane & 15, q4 = lane >> 4;
  const int sr = tid >> 3, sc8 = (tid & 7) * 8;

  const bf16* Kbase = Kb + (size_t)h * SEQ * HD;
  const bf16* Vbase = Vt + (size_t)h * HD * SEQ;
  const f32x4 vzero = {0.f, 0.f, 0.f, 0.f};

#pragma unroll 1
  for (int half = 0; half < 2; ++half) {
    const int qi = half ? jb : (31 - jb);         // heavy q-tile first
    const int q0 = qi * 128;

    bf16x8 aq[2][2];
#pragma unroll
    for (int f = 0; f < 2; f++) {
      const int tq = q0 + w * 32 + f * 16 + c16;
      aq[f][0] = *(const bf16x8*)&Qb[((h * SEQ) + tq) * HD + q4 * 8];
      aq[f][1] = *(const bf16x8*)&Qb[((h * SEQ) + tq) * HD + 32 + q4 * 8];
    }
    const int qg[2] = { q0 + w * 32 + c16, q0 + w * 32 + 16 + c16 };  // lane's q-row per f
    const int qb[2] = { q0 + w * 32,       q0 + w * 32 + 16 };        // wave-uniform min q-row

    f32x4 O[2][4];
    float l_f[2] = {0.f, 0.f};
#pragma unroll
    for (int f = 0; f < 2; f++)
#pragma unroll
      for (int j = 0; j < 4; j++) O[f][j] = vzero;

    const int sEnd = q0 + 64;
    const int sBeg = p * 64;
    if (sBeg <= sEnd) {
      bf16x8 kr0 = *(const bf16x8*)&Kbase[(sBeg + sr) * HD + sc8];
      bf16x8 kr1 = *(const bf16x8*)&Kbase[(sBeg + sr + 32) * HD + sc8];
      bf16x8 vr0 = *(const bf16x8*)&Vbase[sr * SEQ + sBeg + sc8];
      bf16x8 vr1 = *(const bf16x8*)&Vbase[(sr + 32) * SEQ + sBeg + sc8];

      for (int s0 = sBeg; s0 <= sEnd; s0 += NPART * 64) {
        __syncthreads();
        *(bf16x8*)&Ks[sr][sc8]       = kr0;
        *(bf16x8*)&Ks[sr + 32][sc8]  = kr1;
        *(bf16x8*)&Vts[sr][sc8]      = vr0;
        *(bf16x8*)&Vts[sr + 32][sc8] = vr1;
        __syncthreads();

        const int snext = s0 + NPART * 64;
        if (snext <= sEnd) {
          kr0 = *(const bf16x8*)&Kbase[(snext + sr) * HD + sc8];
          kr1 = *(const bf16x8*)&Kbase[(snext + sr + 32) * HD + sc8];
          vr0 = *(const bf16x8*)&Vbase[sr * SEQ + snext + sc8];
          vr1 = *(const bf16x8*)&Vbase[(sr + 32) * SEQ + snext + sc8];
        }

        // K fragments: A-operand [m=s][k=d], read once, shared by both f
        bf16x8 kf0[4], kf1[4];
#pragma unroll
        for (int nt = 0; nt < 4; nt++) {
          kf0[nt] = *(const bf16x8*)&Ks[nt * 16 + c16][q4 * 8];
          kf1[nt] = *(const bf16x8*)&Ks[nt * 16 + c16][32 + q4 * 8];
        }
#pragma unroll
        for (int f = 0; f < 2; f++) {
          // S^T tile: D[m=s][n=q]; lane holds q=c16, s=nt*16+q4*4+rg
          f32x4 S[4];
          __builtin_amdgcn_s_setprio(1);
#pragma unroll
          for (int nt = 0; nt < 4; nt++) {
            f32x4 z = vzero;
            z = MFMA_BF16(kf0[nt], aq[f][0], z);
            z = MFMA_BF16(kf1[nt], aq[f][1], z);
            S[nt] = z;
          }
          __builtin_amdgcn_s_setprio(0);
          float lf = l_f[f];
          if (s0 + 63 <= qb[f]) {
            // interior tile: no lane of this wave/f is masked
#pragma unroll
            for (int nt = 0; nt < 4; nt++) {
#pragma unroll
              for (int rg = 0; rg < 4; rg++) {
                const float pv = exp2f(S[nt][rg]);   // scale*log2e folded into Q
                S[nt][rg] = pv;
                lf += pv;
              }
              bf16x4 pk = { (bf16)S[nt][0], (bf16)S[nt][1], (bf16)S[nt][2], (bf16)S[nt][3] };
              *(bf16x4*)&Pst[w][f * 16 + c16][nt * 16 + q4 * 4] = pk;
            }
          } else if (s0 > qb[f] + 15) {
            // tile entirely above the diagonal for this wave/f: all masked
            const bf16x4 zk = { (bf16)0.f, (bf16)0.f, (bf16)0.f, (bf16)0.f };
#pragma unroll
            for (int nt = 0; nt < 4; nt++)
              *(bf16x4*)&Pst[w][f * 16 + c16][nt * 16 + q4 * 4] = zk;
          } else {
            // diagonal tile: per-element mask
#pragma unroll
            for (int nt = 0; nt < 4; nt++) {
#pragma unroll
              for (int rg = 0; rg < 4; rg++) {
                const int s_g = s0 + nt * 16 + q4 * 4 + rg;
                const float pv = (s_g > qg[f]) ? 0.f : exp2f(S[nt][rg]);
                S[nt][rg] = pv;
                lf += pv;
              }
              bf16x4 pk = { (bf16)S[nt][0], (bf16)S[nt][1], (bf16)S[nt][2], (bf16)S[nt][3] };
              *(bf16x4*)&Pst[w][f * 16 + c16][nt * 16 + q4 * 4] = pk;
            }
          }
          l_f[f] = lf;
        }
        // P fragments (A-op): contiguous b128 from Pst (wave-private)
        bf16x8 ap[2][2];
#pragma unroll
        for (int f = 0; f < 2; f++) {
          ap[f][0] = *(const bf16x8*)&Pst[w][f * 16 + c16][q4 * 8];
          ap[f][1] = *(const bf16x8*)&Pst[w][f * 16 + c16][32 + q4 * 8];
        }
#pragma unroll
        for (int dt = 0; dt < 4; dt++) {
          bf16x8 bv0 = *(const bf16x8*)&Vts[dt * 16 + c16][q4 * 8];
          bf16x8 bv1 = *(const bf16x8*)&Vts[dt * 16 + c16][32 + q4 * 8];
          __builtin_amdgcn_s_setprio(1);
#pragma unroll
          for (int f = 0; f < 2; f++) {
            O[f][dt] = MFMA_BF16(ap[f][0], bv0, O[f][dt]);
            O[f][dt] = MFMA_BF16(ap[f][1], bv1, O[f][dt]);
          }
          __builtin_amdgcn_s_setprio(0);
        }
      }
    }

    // l: lane holds full sum for q-row c16 (per f) over its (q4, nt, rg) share
#pragma unroll
    for (int f = 0; f < 2; f++) {
      float l = l_f[f];
      l += __shfl_xor(l, 16, 64);
      l += __shfl_xor(l, 32, 64);
      l_f[f] = l;
    }
    const int u = ((h * 32 + qi) * NPART + p);
    bf16* Op = Opart + (size_t)u * 8192;            // 128 x 64
#pragma unroll
    for (int f = 0; f < 2; f++)
#pragma unroll
      for (int dt = 0; dt < 4; dt++)
#pragma unroll
        for (int rg = 0; rg < 4; rg++)
          Op[(w * 32 + f * 16 + q4 * 4 + rg) * 64 + dt * 16 + c16] = (bf16)O[f][dt][rg];
    if (lane < 32) {                                // q4 == 0 -> one writer per row
      if (q4 == 0) {
#pragma unroll
        for (int f = 0; f < 2; f++)
          Lpart[u * 128 + w * 32 + f * 16 + c16] = l_f[f];
      }
    }
  }
}

// ---------------------------------------------------------------------------
// Combine: Y = (sum_p O_p) / (sum_p l_p). Block per 64-row chunk x head.
// ---------------------------------------------------------------------------
__global__ __launch_bounds__(256) void flash_combine(
    const bf16* __restrict__ Opart, const float* __restrict__ Lpart,
    bf16* __restrict__ Y)
{
  const int q64 = blockIdx.x, h = blockIdx.y;
  const int qi = q64 >> 1, roff = (q64 & 1) * 64;
  const int row = threadIdx.x >> 2, cg = (threadIdx.x & 3) * 16;
  const int u0 = (h * 32 + qi) * NPART;
  const int r128 = roff + row;
  float lsum = 0.f;
#pragma unroll
  for (int p = 0; p < NPART; p++) lsum += Lpart[(u0 + p) * 128 + r128];
  const float inv = 1.0f / lsum;
  const bf16* O0 = Opart + (size_t)u0 * 8192 + r128 * 64 + cg;
  bf16* yp = Y + (size_t)(q64 * 64 + row) * DM + h * HD + cg;
#pragma unroll
  for (int j = 0; j < 16; j += 8) {
    float s[8] = {0, 0, 0, 0, 0, 0, 0, 0};
#pragma unroll
    for (int p = 0; p < NPART; p++) {
      bf16x8 a = *(const bf16x8*)(O0 + p * 8192 + j);
#pragma unroll
      for (int e = 0; e < 8; e++) s[e] += (float)a[e];
    }
#pragma unroll
    for (int e = 0; e < 8; e++) yp[j + e] = (bf16)(s[e] * inv);
  }
}

// ---------------------------------------------------------------------------
extern "C" void kernel_launch(void* const* d_in, const int* in_sizes, int n_in,
                              void* d_out, int out_size, void* d_ws, size_t ws_size,
                              hipStream_t stream)
{
  (void)in_sizes; (void)n_in; (void)out_size; (void)ws_size;
  const float* x      = (const float*)d_in[0];
  const float* qkvw   = (const float*)d_in[1];
  const float* cprojw = (const float*)d_in[2];
  float* outp = (float*)d_out;

  const int NX = SEQ * DM, NW = NQKV * DM, NP = DM * DM;

  char* ws = (char*)d_ws;
  bf16*  xb    = (bf16*)(ws);                       // 6,291,456
  bf16*  wqkv  = (bf16*)(ws + 6291456);             // 3,538,944
  bf16*  wproj = (bf16*)(ws + 9830400);             // 1,179,648
  bf16*  Q     = (bf16*)(ws + 11010048);            // 6,291,456
  bf16*  K     = (bf16*)(ws + 17301504);            // 6,291,456
  bf16*  Vt    = (bf16*)(ws + 23592960);            // 6,291,456
  bf16*  Y     = (bf16*)(ws + 29884416);            // 6,291,456
  bf16*  Opart = (bf16*)(ws + 36175872);            // 25,165,824 (1536 x 8192 bf16)
  float* Lpart = (float*)(ws + 61341696);           //    786,432  (total 62.1 MB)

  convert_in<<<dim3(NX / 2048), 256, 0, stream>>>(x,      xb,    NX);
  convert_in<<<dim3(NW / 2048), 256, 0, stream>>>(qkvw,   wqkv,  NW);
  convert_in<<<dim3(NP / 2048), 256, 0, stream>>>(cprojw, wproj, NP);

  gemm_qkv     <<<dim3(SEQ / 128, NQKV / 128), 256, 0, stream>>>(xb, wqkv, Q, K, Vt);
  flash_partial<<<dim3(16, NH, NPART),         256, 0, stream>>>(Q, K, Vt, Opart, Lpart);
  flash_combine<<<dim3(SEQ / 64, NH),          256, 0, stream>>>(Opart, Lpart, Y);
  gemm_proj    <<<dim3(SEQ / 128, DM / 128),   256, 0, stream>>>(Y, wproj, outp);
}